// Round 3
// baseline (100.234 us; speedup 1.0000x reference)
//
#include <hip/hip_runtime.h>
#include <math.h>

#define CCH  32
#define NPIX 4096   // 64*64
#define BB   2

// ---------------------------------------------------------------------------
// KA: fused Gram + weight-fold.
//   g[c]   = sum_m Xhat[b,i,m] * X[b,c,m]          (one (b,i) row per block)
//   wEff[b,o,i,k] = (1/sqrt(C)) * sum_c w[o,c,k] * g[c]
// Also zeroes the stats accumulators (block 0) before KB runs.
// grid: B*32 = 64 blocks, 256 threads.
// ---------------------------------------------------------------------------
__global__ __launch_bounds__(256) void k_gram_weff(const float* __restrict__ X,
                                                   const float* __restrict__ Xh,
                                                   const float* __restrict__ wConv,
                                                   float* __restrict__ wEff,
                                                   float* __restrict__ sums) {
    int blk = blockIdx.x;           // b*32 + i
    int b = blk >> 5, i = blk & 31;
    int t = threadIdx.x;

    if (blk == 0 && t < 64) sums[t] = 0.f;   // KB (later launch) consumes these

    __shared__ float xh_lds[NPIX];
    {
        float4* dst = (float4*)xh_lds;
        const float4* src = (const float4*)(Xh + (size_t)(b*CCH + i) * NPIX);
        #pragma unroll
        for (int k = 0; k < 4; ++k) dst[t + k*256] = src[t + k*256];
    }
    __syncthreads();

    int c = t >> 3;                 // 0..31 : which X channel this group dots
    int s = t & 7;                  // 0..7  : position within the 8-lane group
    const float4* xc = (const float4*)(X + (size_t)(b*CCH + c) * NPIX);
    const float4* xh4 = (const float4*)xh_lds;
    float acc = 0.f;
    #pragma unroll 8
    for (int k = 0; k < 128; ++k) {
        float4 v = xc[s + k*8];
        float4 h = xh4[s + k*8];
        acc += v.x*h.x + v.y*h.y + v.z*h.z + v.w*h.w;
    }
    acc += __shfl_down(acc, 4, 8);
    acc += __shfl_down(acc, 2, 8);
    acc += __shfl_down(acc, 1, 8);

    __shared__ float g[CCH];
    if (s == 0) g[c] = acc;
    __syncthreads();

    // 288 outputs (o,k) with 256 threads -> strided loop (round-2 bug was
    // `if (t < 288)` which left o>=28,k>=4 unwritten = ws poison).
    for (int r = t; r < CCH*9; r += 256) {
        int o = r / 9, k = r - 9*(r/9);
        float sacc = 0.f;
        #pragma unroll
        for (int cc = 0; cc < CCH; ++cc)
            sacc += wConv[(o*CCH + cc)*9 + k] * g[cc];
        wEff[((b*CCH + o)*CCH + i)*9 + k] = sacc * 0.17677669529663687f;
    }
}

// ---------------------------------------------------------------------------
// KB: direct 3x3 conv with folded weights + fused BN-stats (atomics) +
//     fused 2x2 window max AND min (so BN+ReLU+pool can be applied later for
//     either sign of the BN scale).  No full-res conv output is materialized.
// grid: B*32*16 blocks = (b, o, 4-row tile); 256 thr = 4 rows x 64 cols.
// ---------------------------------------------------------------------------
__global__ __launch_bounds__(256) void k_conv(const float* __restrict__ X,
                                              const float* __restrict__ wEff,
                                              const float* __restrict__ bias,
                                              float* __restrict__ poolMax,
                                              float* __restrict__ poolMin,
                                              float* __restrict__ sums) {
    int blk = blockIdx.x;
    int b   = blk / 512;
    int rem = blk - b*512;
    int o   = rem >> 4;
    int rt  = rem & 15;

    __shared__ float lw[CCH*9];
    const float* wsrc = wEff + (size_t)((b*CCH + o)*CCH)*9;
    for (int r = threadIdx.x; r < CCH*9; r += 256) lw[r] = wsrc[r];
    __syncthreads();

    int x = threadIdx.x & 63;
    int y = rt*4 + (threadIdx.x >> 6);
    int xl = max(x-1, 0), xr = min(x+1, 63);
    int yu = max(y-1, 0), yd = min(y+1, 63);
    float mxl = (x > 0)  ? 1.f : 0.f;
    float mxr = (x < 63) ? 1.f : 0.f;
    float myu = (y > 0)  ? 1.f : 0.f;
    float myd = (y < 63) ? 1.f : 0.f;
    float m0 = myu*mxl, m1 = myu, m2 = myu*mxr;
    float m3 = mxl,               m5 = mxr;
    float m6 = myd*mxl, m7 = myd, m8 = myd*mxr;

    const float* plane = X + (size_t)b*CCH*NPIX;
    int ou = yu*64, o0 = y*64, od = yd*64;
    float acc = bias[o];
    #pragma unroll 4
    for (int i = 0; i < CCH; ++i) {
        const float* p   = plane + i*NPIX;
        const float* lwi = lw + i*9;
        float v0 = p[ou + xl] * m0;
        float v1 = p[ou + x ] * m1;
        float v2 = p[ou + xr] * m2;
        float v3 = p[o0 + xl] * m3;
        float v4 = p[o0 + x ];
        float v5 = p[o0 + xr] * m5;
        float v6 = p[od + xl] * m6;
        float v7 = p[od + x ] * m7;
        float v8 = p[od + xr] * m8;
        acc = fmaf(lwi[0], v0, acc);
        acc = fmaf(lwi[1], v1, acc);
        acc = fmaf(lwi[2], v2, acc);
        acc = fmaf(lwi[3], v3, acc);
        acc = fmaf(lwi[4], v4, acc);
        acc = fmaf(lwi[5], v5, acc);
        acc = fmaf(lwi[6], v6, acc);
        acc = fmaf(lwi[7], v7, acc);
        acc = fmaf(lwi[8], v8, acc);
    }

    __shared__ float tile[256];          // [4 rows][64 cols]
    tile[threadIdx.x] = acc;

    // block-level sum / sumsq for BN stats
    float s1 = acc, s2 = acc*acc;
    #pragma unroll
    for (int off = 32; off > 0; off >>= 1) {
        s1 += __shfl_down(s1, off, 64);
        s2 += __shfl_down(s2, off, 64);
    }
    __shared__ float r1[4], r2[4];
    int lane = threadIdx.x & 63, wid = threadIdx.x >> 6;
    if (lane == 0) { r1[wid] = s1; r2[wid] = s2; }
    __syncthreads();
    if (threadIdx.x == 0) {
        atomicAdd(&sums[o],      r1[0] + r1[1] + r1[2] + r1[3]);
        atomicAdd(&sums[32 + o], r2[0] + r2[1] + r2[2] + r2[3]);
    }

    // 2x2 window max & min (pool applied after BN affine in KC, sign-aware)
    if (threadIdx.x < 64) {
        int py = threadIdx.x >> 5;       // 0..1 pooled row within this tile
        int px = threadIdx.x & 31;
        const float* row0 = &tile[(2*py)*64 + 2*px];
        const float* row1 = &tile[(2*py+1)*64 + 2*px];
        float a0 = row0[0], a1 = row0[1], b0 = row1[0], b1 = row1[1];
        float mx = fmaxf(fmaxf(a0, a1), fmaxf(b0, b1));
        float mn = fminf(fminf(a0, a1), fminf(b0, b1));
        size_t pidx = (size_t)(b*CCH + o)*1024 + (rt*2 + py)*32 + px;
        poolMax[pidx] = mx;
        poolMin[pidx] = mn;
    }
}

// ---------------------------------------------------------------------------
// KC: finalize BN scale/shift from sums, apply BN+ReLU to the pooled plane
//     (max if scale>=0, min if scale<0), bilinear align-corners x2 upsample,
//     *2, + 0.2*f.  grid: B*32 blocks (b,c), 256 threads.
// ---------------------------------------------------------------------------
__global__ __launch_bounds__(256) void k_tail(const float* __restrict__ poolMax,
                                              const float* __restrict__ poolMin,
                                              const float* __restrict__ sums,
                                              const float* __restrict__ gamma,
                                              const float* __restrict__ beta,
                                              const float* __restrict__ f,
                                              float* __restrict__ out) {
    int b = blockIdx.x >> 5;
    int c = blockIdx.x & 31;
    float S  = sums[c];
    float S2 = sums[32 + c];
    const float invN = 1.f / (BB * NPIX);
    float mean = S * invN;
    float var  = S2 * invN - mean*mean;
    float sc = gamma[c] / sqrtf(var + 1e-5f);
    float sh = beta[c] - mean * sc;

    const float* psel = (sc >= 0.f ? poolMax : poolMin) + (size_t)(b*CCH + c)*1024;
    __shared__ float pool[1024];
    int t = threadIdx.x;
    #pragma unroll
    for (int q = 0; q < 4; ++q) {
        int idx = t + q*256;
        pool[idx] = fmaxf(fmaf(psel[idx], sc, sh), 0.f);
    }
    __syncthreads();

    const float r = 31.f / 63.f;            // align_corners ratio
    const float* fp = f   + (size_t)(b*CCH + c)*NPIX;
    float*       op = out + (size_t)(b*CCH + c)*NPIX;
    #pragma unroll
    for (int q = 0; q < 16; ++q) {
        int idx = t + q*256;                // output pixel 0..4095
        int oy = idx >> 6, ox = idx & 63;
        float ysf = (float)oy * r;
        float xsf = (float)ox * r;
        int y0 = (int)ysf;
        int x0 = (int)xsf;
        float wy = ysf - (float)y0;
        float wx = xsf - (float)x0;
        int y1 = min(y0 + 1, 31);
        int x1 = min(x0 + 1, 31);
        float p00 = pool[y0*32 + x0];
        float p01 = pool[y0*32 + x1];
        float p10 = pool[y1*32 + x0];
        float p11 = pool[y1*32 + x1];
        float top = p00 + (p01 - p00) * wx;
        float bot = p10 + (p11 - p10) * wx;
        float val = 2.f * (top + (bot - top) * wy);
        op[idx] = val + 0.2f * fp[idx];
    }
}

// ---------------------------------------------------------------------------
extern "C" void kernel_launch(void* const* d_in, const int* in_sizes, int n_in,
                              void* d_out, int out_size, void* d_ws, size_t ws_size,
                              hipStream_t stream) {
    const float* X   = (const float*)d_in[0];  // X_tnext      (2,32,64,64)
    const float* Xh  = (const float*)d_in[1];  // X_hat_tnext  (2,32,64,64)
    const float* f   = (const float*)d_in[2];  // f_tprev_t    (2,32,64,64)
    const float* wC  = (const float*)d_in[3];  // conv_w       (32,32,3,3)
    const float* bC  = (const float*)d_in[4];  // conv_b       (32,)
    const float* gam = (const float*)d_in[5];  // bn_gamma     (32,)
    const float* bet = (const float*)d_in[6];  // bn_beta      (32,)
    float* out = (float*)d_out;

    float* W       = (float*)d_ws;
    float* wEff    = W;                 // 18432 floats  (B,O,C,9)
    float* sums    = W + 18432;         // 64 floats: [0..31]=sum, [32..63]=sumsq
    float* poolMax = W + 18496;         // 65536 floats (B,C,32,32)
    float* poolMin = W + 84032;         // 65536 floats

    hipLaunchKernelGGL(k_gram_weff, dim3(64),   dim3(256), 0, stream, X, Xh, wC, wEff, sums);
    hipLaunchKernelGGL(k_conv,      dim3(1024), dim3(256), 0, stream, X, wEff, bC, poolMax, poolMin, sums);
    hipLaunchKernelGGL(k_tail,      dim3(64),   dim3(256), 0, stream, poolMax, poolMin, sums, gam, bet, f, out);
}